// Round 6
// baseline (1054.186 us; speedup 1.0000x reference)
//
#include <hip/hip_runtime.h>

// LightGCN encoder, round 6: pull-CSR SpMM (unchanged hot loop) + direct CSR
// build (per-row histogram -> parallel scan -> one-pass scatter) and fused
// init (layer-1 gathers straight from user/item and seeds acc with a store).
//
// Round-5 post-mortem: SpMM is now 170us/layer (good), but preprocess+init
// was 366us of the 878us total - bucket hist/scan/scatter/sort machinery left
// over from the abandoned LDS-atomic design. Replace with a direct build.

#define USER_NUM 100000
#define ITEM_NUM 50000
#define N_NODES (USER_NUM + ITEM_NUM)
#define EMB 64
#define NFLOAT (N_NODES * EMB)

#define SCAN_CHUNK 1024
#define SCAN_BLOCKS ((N_NODES + SCAN_CHUNK - 1) / SCAN_CHUNK)   // 147

// ---------------- per-row degree histogram ----------------
__global__ __launch_bounds__(256) void deg_hist(const int* __restrict__ row,
                                                int* __restrict__ deg, int nnz) {
    int stride = gridDim.x * blockDim.x;
    for (int i = blockIdx.x * blockDim.x + threadIdx.x; i < nnz; i += stride)
        atomicAdd(&deg[row[i]], 1);
}

// ---------------- scan step 1: per-block partial sums (1024 rows/block) ----------------
__global__ __launch_bounds__(256) void scan_partial(const int* __restrict__ deg,
                                                    int* __restrict__ bsum) {
    __shared__ int sh[256];
    const int b = blockIdx.x;
    const int base = b * SCAN_CHUNK + threadIdx.x * 4;
    int s = 0;
    #pragma unroll
    for (int j = 0; j < 4; ++j) {
        int i = base + j;
        if (i < N_NODES) s += deg[i];
    }
    sh[threadIdx.x] = s;
    __syncthreads();
    for (int off = 128; off > 0; off >>= 1) {
        if (threadIdx.x < off) sh[threadIdx.x] += sh[threadIdx.x + off];
        __syncthreads();
    }
    if (threadIdx.x == 0) bsum[b] = sh[0];
}

// ---------------- scan step 2: serial top-level exclusive scan (147 entries) ----------------
__global__ void scan_top(int* __restrict__ bsum) {
    if (threadIdx.x == 0) {
        int run = 0;
        for (int b = 0; b < SCAN_BLOCKS; ++b) {
            int c = bsum[b]; bsum[b] = run; run += c;
        }
    }
}

// ---------------- scan step 3: in-block exclusive scan + add-back -> rowptr/cursor ----------------
__global__ __launch_bounds__(256) void scan_write(const int* __restrict__ deg,
                                                  const int* __restrict__ bsum,
                                                  int* __restrict__ rowptr,
                                                  int* __restrict__ cursor, int nnz) {
    __shared__ int sh[256];
    const int b = blockIdx.x;
    const int base = b * SCAN_CHUNK + threadIdx.x * 4;
    int d[4];
    int tsum = 0;
    #pragma unroll
    for (int j = 0; j < 4; ++j) {
        int i = base + j;
        d[j] = (i < N_NODES) ? deg[i] : 0;
        tsum += d[j];
    }
    sh[threadIdx.x] = tsum;
    __syncthreads();
    // Hillis-Steele inclusive scan over 256 thread sums
    for (int off = 1; off < 256; off <<= 1) {
        int v = (threadIdx.x >= off) ? sh[threadIdx.x - off] : 0;
        __syncthreads();
        sh[threadIdx.x] += v;
        __syncthreads();
    }
    int start = bsum[b] + sh[threadIdx.x] - tsum;   // exclusive prefix for this thread
    #pragma unroll
    for (int j = 0; j < 4; ++j) {
        int i = base + j;
        if (i < N_NODES) {
            rowptr[i] = start;
            cursor[i] = start;
            start += d[j];
        }
    }
    if (b == 0 && threadIdx.x == 0) rowptr[N_NODES] = nnz;
}

// ---------------- one-pass scatter into CSR slots ----------------
__global__ __launch_bounds__(256) void csr_scatter(const int* __restrict__ row,
                                                   const int* __restrict__ col,
                                                   const float* __restrict__ vals,
                                                   int* __restrict__ cursor,
                                                   uint2* __restrict__ bkv, int nnz) {
    int stride = gridDim.x * blockDim.x;
    for (int i = blockIdx.x * blockDim.x + threadIdx.x; i < nnz; i += stride) {
        int r = row[i];
        int pos = atomicAdd(&cursor[r], 1);
        bkv[pos] = make_uint2((unsigned)col[i], __float_as_uint(vals[i]));
    }
}

// ---------------- pull SpMM: one wave per output row ----------------
// lane = dim; edges staged lane-parallel, shfl-broadcast, gathers 8-deep.
// FIRST: gather from user/item directly (no h0) and seed acc with a store.
// LAST:  skip h_next write.
template <bool FIRST, bool LAST>
__global__ __launch_bounds__(256) void lgcn_spmm_pull(const uint2* __restrict__ bkv,
                                                      const int* __restrict__ rowptr,
                                                      const float* __restrict__ xu,
                                                      const float* __restrict__ xi,
                                                      float* __restrict__ h_next,
                                                      float* __restrict__ acc) {
    const int lane = threadIdx.x & 63;
    const int wid = threadIdx.x >> 6;
    const int r = blockIdx.x * 4 + wid;
    if (r >= N_NODES) return;

    const int s = rowptr[r];
    const int deg = rowptr[r + 1] - s;
    const uint2* ebase = bkv + s;

    float a = 0.f;
    for (int base = 0; base < deg; base += 64) {
        int n = deg - base;
        if (n > 64) n = 64;
        uint2 kv = make_uint2(0u, 0u);
        if (lane < n) kv = ebase[base + lane];
        int k = 0;
        for (; k + 8 <= n; k += 8) {
            float xs0, xs1, xs2, xs3, xs4, xs5, xs6, xs7;
            float v0, v1, v2, v3, v4, v5, v6, v7;
            {
                int c;
#define GATHER(J, XS, V)                                                     \
                c = __shfl((int)kv.x, k + J);                                \
                V = __uint_as_float(__shfl((int)kv.y, k + J));               \
                if (FIRST) {                                                 \
                    const float* xp = (c < USER_NUM)                         \
                        ? (xu + ((size_t)c << 6))                            \
                        : (xi + ((size_t)(c - USER_NUM) << 6));              \
                    XS = xp[lane];                                           \
                } else {                                                     \
                    XS = xu[((size_t)c << 6) + lane];                        \
                }
                GATHER(0, xs0, v0) GATHER(1, xs1, v1)
                GATHER(2, xs2, v2) GATHER(3, xs3, v3)
                GATHER(4, xs4, v4) GATHER(5, xs5, v5)
                GATHER(6, xs6, v6) GATHER(7, xs7, v7)
#undef GATHER
            }
            a = fmaf(v0, xs0, a); a = fmaf(v1, xs1, a);
            a = fmaf(v2, xs2, a); a = fmaf(v3, xs3, a);
            a = fmaf(v4, xs4, a); a = fmaf(v5, xs5, a);
            a = fmaf(v6, xs6, a); a = fmaf(v7, xs7, a);
        }
        for (; k < n; ++k) {
            int c = __shfl((int)kv.x, k);
            float v = __uint_as_float(__shfl((int)kv.y, k));
            float xs;
            if (FIRST) {
                const float* xp = (c < USER_NUM) ? (xu + ((size_t)c << 6))
                                                 : (xi + ((size_t)(c - USER_NUM) << 6));
                xs = xp[lane];
            } else {
                xs = xu[((size_t)c << 6) + lane];
            }
            a = fmaf(v, xs, a);
        }
    }

    const int o = (r << 6) + lane;
    if (!LAST) h_next[o] = a;
    if (FIRST) {
        // seed acc = 0.25*(ego[r] + h1[r]); coalesced ego row read
        float ego = (r < USER_NUM) ? xu[o] : xi[(((size_t)(r - USER_NUM)) << 6) + lane];
        acc[o] = 0.25f * (ego + a);
    } else {
        acc[o] += 0.25f * a;
    }
}

extern "C" void kernel_launch(void* const* d_in, const int* in_sizes, int n_in,
                              void* d_out, int out_size, void* d_ws, size_t ws_size,
                              hipStream_t stream) {
    const float* user_emb = (const float*)d_in[0];
    const float* item_emb = (const float*)d_in[1];
    const int* adj_row = (const int*)d_in[2];
    const int* adj_col = (const int*)d_in[3];
    const float* adj_vals = (const float*)d_in[4];
    const int nnz = in_sizes[2];

    float* acc = (float*)d_out;

    char* ws = (char*)d_ws;
    float* h1 = (float*)ws;                       ws += (size_t)NFLOAT * 4;
    float* h2 = (float*)ws;                       ws += (size_t)NFLOAT * 4;
    uint2* bkv = (uint2*)ws;                      ws += (size_t)nnz * 8;
    int* deg = (int*)ws;                          ws += (size_t)N_NODES * 4;
    int* rowptr = (int*)ws;                       ws += (size_t)(N_NODES + 1) * 4;
    int* cursor = (int*)ws;                       ws += (size_t)N_NODES * 4;
    int* bsum = (int*)ws;                         ws += (size_t)SCAN_BLOCKS * 4;

    // --- build CSR directly
    hipMemsetAsync(deg, 0, (size_t)N_NODES * 4, stream);
    deg_hist<<<2048, 256, 0, stream>>>(adj_row, deg, nnz);
    scan_partial<<<SCAN_BLOCKS, 256, 0, stream>>>(deg, bsum);
    scan_top<<<1, 64, 0, stream>>>(bsum);
    scan_write<<<SCAN_BLOCKS, 256, 0, stream>>>(deg, bsum, rowptr, cursor, nnz);
    csr_scatter<<<2048, 256, 0, stream>>>(adj_row, adj_col, adj_vals,
                                          cursor, bkv, nnz);

    // --- 3 propagation layers (pull); layer 1 reads ego directly, seeds acc
    const int grid = (N_NODES + 3) / 4;
    lgcn_spmm_pull<true,  false><<<grid, 256, 0, stream>>>(bkv, rowptr, user_emb, item_emb, h1, acc);
    lgcn_spmm_pull<false, false><<<grid, 256, 0, stream>>>(bkv, rowptr, h1, nullptr, h2, acc);
    lgcn_spmm_pull<false, true ><<<grid, 256, 0, stream>>>(bkv, rowptr, h2, nullptr, nullptr, acc);
}

// Round 8
// 815.268 us; speedup vs baseline: 1.2931x; 1.2931x over previous
//
#include <hip/hip_runtime.h>

// LightGCN encoder, round 8 — identical to round 7 (round-7 run hit a GPU
// acquisition timeout; the kernel never executed).
//
// Round-6 post-mortem: per-edge GLOBAL atomics cost ~240us/pass (deg_hist
// ~240us; csr_scatter 250us with 64B-line write amplification, WRITE=297MB).
// Revert to round-5's atomic-free structure (LDS-privatized hist + bucket
// scatter + per-bucket counting sort), tuned: 512-row buckets (NB2=293) give
// 224B scatter runs AND 293x16-wave sort parallelism; the sort now emits
// rowptr directly. Keep round-6's fused init (layer-1 gathers from user/item,
// seeds acc) and the proven 8-deep pull SpMM hot loop.

#define USER_NUM 100000
#define ITEM_NUM 50000
#define N_NODES (USER_NUM + ITEM_NUM)
#define EMB 64
#define NFLOAT (N_NODES * EMB)

#define SHIFT2 9
#define RPB 512                               // rows per bucket
#define NB2 ((N_NODES + RPB - 1) / RPB)       // 293 buckets
#define COLMASK 0x3FFFF                       // col < 150000 < 2^18

// ---------------- bucket histogram (LDS-privatized, no per-edge global atomics)
__global__ __launch_bounds__(256) void k_hist(const int* __restrict__ row,
                                              int* __restrict__ ghist, int nnz) {
    __shared__ int cnt[NB2];
    for (int t = threadIdx.x; t < NB2; t += 256) cnt[t] = 0;
    __syncthreads();
    int stride = gridDim.x * blockDim.x;
    for (int i = blockIdx.x * blockDim.x + threadIdx.x; i < nnz; i += stride)
        atomicAdd(&cnt[row[i] >> SHIFT2], 1);
    __syncthreads();
    for (int t = threadIdx.x; t < NB2; t += 256) {
        int c = cnt[t];
        if (c) atomicAdd(&ghist[t], c);       // 512 blocks * 293 = 150k merges
    }
}

// ---------------- bucket exclusive scan (LDS-staged, serial core over 293)
__global__ __launch_bounds__(512) void k_top(const int* __restrict__ ghist,
                                             int* __restrict__ bstart,
                                             int* __restrict__ bcursor, int nnz) {
    __shared__ int buf[NB2];
    for (int t = threadIdx.x; t < NB2; t += 512) buf[t] = ghist[t];
    __syncthreads();
    if (threadIdx.x == 0) {
        int run = 0;
        for (int b = 0; b < NB2; ++b) { int c = buf[b]; buf[b] = run; run += c; }
    }
    __syncthreads();
    for (int t = threadIdx.x; t < NB2; t += 512) {
        bstart[t] = buf[t];
        bcursor[t] = buf[t];
    }
    if (threadIdx.x == 0) bstart[NB2] = nnz;
}

// ---------------- phase 1: scatter edges into bucket-contiguous packed array
// Two LDS-count passes; per (block,bucket) writes are contiguous ~224B runs.
#define SC_EPT 32
#define SC_CHUNK (256 * SC_EPT)
__global__ __launch_bounds__(256) void k_scat1(const int* __restrict__ row,
                                               const int* __restrict__ col,
                                               const float* __restrict__ vals,
                                               int* __restrict__ bcursor,
                                               uint2* __restrict__ packed, int nnz) {
    __shared__ int cnt[NB2];
    __shared__ int base[NB2];
    for (int t = threadIdx.x; t < NB2; t += 256) cnt[t] = 0;
    __syncthreads();
    long long start = (long long)blockIdx.x * SC_CHUNK;
    for (int k = 0; k < SC_EPT; ++k) {
        long long i = start + k * 256 + threadIdx.x;
        if (i < nnz) atomicAdd(&cnt[row[i] >> SHIFT2], 1);
    }
    __syncthreads();
    for (int t = threadIdx.x; t < NB2; t += 256) {
        int c = cnt[t];
        base[t] = c ? atomicAdd(&bcursor[t], c) : 0;
        cnt[t] = 0;
    }
    __syncthreads();
    for (int k = 0; k < SC_EPT; ++k) {
        long long i = start + k * 256 + threadIdx.x;
        if (i < nnz) {
            int r = row[i];
            int b = r >> SHIFT2;
            int l = atomicAdd(&cnt[b], 1);
            packed[base[b] + l] =
                make_uint2(((unsigned)(r & (RPB - 1)) << 18) | (unsigned)col[i],
                           __float_as_uint(vals[i]));
        }
    }
}

// ---------------- phase 2: per-bucket counting sort -> final CSR + rowptr
// One block (16 waves) per bucket; all counters/cursors in LDS; scatter spans
// only the bucket's ~131KB slice of bkv (L2-resident).
__global__ __launch_bounds__(1024) void k_sort(const uint2* __restrict__ packed,
                                               const int* __restrict__ bstart,
                                               uint2* __restrict__ bkv,
                                               int* __restrict__ rowptr, int nnz) {
    __shared__ int cnt[RPB];
    __shared__ int scn[RPB];
    const int b = blockIdx.x;
    const int s = bstart[b], e = bstart[b + 1];
    if (threadIdx.x < RPB) cnt[threadIdx.x] = 0;
    __syncthreads();
    for (int i = s + threadIdx.x; i < e; i += 1024)
        atomicAdd(&cnt[packed[i].x >> 18], 1);
    __syncthreads();
    if (threadIdx.x < RPB) scn[threadIdx.x] = cnt[threadIdx.x];
    __syncthreads();
    // Hillis-Steele inclusive scan over RPB=512 counters
    for (int off = 1; off < RPB; off <<= 1) {
        int v = 0;
        if (threadIdx.x < RPB && threadIdx.x >= off) v = scn[threadIdx.x - off];
        __syncthreads();
        if (threadIdx.x < RPB) scn[threadIdx.x] += v;
        __syncthreads();
    }
    const int grow0 = b << SHIFT2;
    if (threadIdx.x < RPB) {
        int start = s + scn[threadIdx.x] - cnt[threadIdx.x];   // exclusive
        int gr = grow0 + threadIdx.x;
        if (gr < N_NODES) rowptr[gr] = start;
        cnt[threadIdx.x] = start;                              // becomes cursor
    }
    if (b == 0 && threadIdx.x == 0) rowptr[N_NODES] = nnz;
    __syncthreads();
    for (int i = s + threadIdx.x; i < e; i += 1024) {
        uint2 kv = packed[i];
        int lr = kv.x >> 18;
        int pos = atomicAdd(&cnt[lr], 1);                      // LDS cursor
        bkv[pos] = make_uint2(kv.x & COLMASK, kv.y);
    }
}

// ---------------- pull SpMM: one wave per output row (unchanged hot loop)
template <bool FIRST, bool LAST>
__global__ __launch_bounds__(256) void lgcn_spmm_pull(const uint2* __restrict__ bkv,
                                                      const int* __restrict__ rowptr,
                                                      const float* __restrict__ xu,
                                                      const float* __restrict__ xi,
                                                      float* __restrict__ h_next,
                                                      float* __restrict__ acc) {
    const int lane = threadIdx.x & 63;
    const int wid = threadIdx.x >> 6;
    const int r = blockIdx.x * 4 + wid;
    if (r >= N_NODES) return;

    const int s = rowptr[r];
    const int deg = rowptr[r + 1] - s;
    const uint2* ebase = bkv + s;

    float a = 0.f;
    for (int base = 0; base < deg; base += 64) {
        int n = deg - base;
        if (n > 64) n = 64;
        uint2 kv = make_uint2(0u, 0u);
        if (lane < n) kv = ebase[base + lane];
        int k = 0;
        for (; k + 8 <= n; k += 8) {
            float xs0, xs1, xs2, xs3, xs4, xs5, xs6, xs7;
            float v0, v1, v2, v3, v4, v5, v6, v7;
            {
                int c;
#define GATHER(J, XS, V)                                                     \
                c = __shfl((int)kv.x, k + J);                                \
                V = __uint_as_float(__shfl((int)kv.y, k + J));               \
                if (FIRST) {                                                 \
                    const float* xp = (c < USER_NUM)                         \
                        ? (xu + ((size_t)c << 6))                            \
                        : (xi + ((size_t)(c - USER_NUM) << 6));              \
                    XS = xp[lane];                                           \
                } else {                                                     \
                    XS = xu[((size_t)c << 6) + lane];                        \
                }
                GATHER(0, xs0, v0) GATHER(1, xs1, v1)
                GATHER(2, xs2, v2) GATHER(3, xs3, v3)
                GATHER(4, xs4, v4) GATHER(5, xs5, v5)
                GATHER(6, xs6, v6) GATHER(7, xs7, v7)
#undef GATHER
            }
            a = fmaf(v0, xs0, a); a = fmaf(v1, xs1, a);
            a = fmaf(v2, xs2, a); a = fmaf(v3, xs3, a);
            a = fmaf(v4, xs4, a); a = fmaf(v5, xs5, a);
            a = fmaf(v6, xs6, a); a = fmaf(v7, xs7, a);
        }
        for (; k < n; ++k) {
            int c = __shfl((int)kv.x, k);
            float v = __uint_as_float(__shfl((int)kv.y, k));
            float xs;
            if (FIRST) {
                const float* xp = (c < USER_NUM) ? (xu + ((size_t)c << 6))
                                                 : (xi + ((size_t)(c - USER_NUM) << 6));
                xs = xp[lane];
            } else {
                xs = xu[((size_t)c << 6) + lane];
            }
            a = fmaf(v, xs, a);
        }
    }

    const int o = (r << 6) + lane;
    if (!LAST) h_next[o] = a;
    if (FIRST) {
        float ego = (r < USER_NUM) ? xu[o] : xi[(((size_t)(r - USER_NUM)) << 6) + lane];
        acc[o] = 0.25f * (ego + a);
    } else {
        acc[o] += 0.25f * a;
    }
}

extern "C" void kernel_launch(void* const* d_in, const int* in_sizes, int n_in,
                              void* d_out, int out_size, void* d_ws, size_t ws_size,
                              hipStream_t stream) {
    const float* user_emb = (const float*)d_in[0];
    const float* item_emb = (const float*)d_in[1];
    const int* adj_row = (const int*)d_in[2];
    const int* adj_col = (const int*)d_in[3];
    const float* adj_vals = (const float*)d_in[4];
    const int nnz = in_sizes[2];

    float* acc = (float*)d_out;

    char* ws = (char*)d_ws;
    float* h1 = (float*)ws;                       ws += (size_t)NFLOAT * 4;
    char* region2 = ws;                           ws += (size_t)NFLOAT * 4;
    uint2* packed = (uint2*)region2;              // dead after k_sort
    float* h2 = (float*)region2;                  // reuses packed's space
    uint2* bkv = (uint2*)ws;                      ws += (size_t)nnz * 8;
    int* rowptr = (int*)ws;                       ws += (size_t)(N_NODES + 1) * 4;
    int* ghist = (int*)ws;                        ws += (size_t)NB2 * 4;
    int* bstart = (int*)ws;                       ws += (size_t)(NB2 + 1) * 4;
    int* bcursor = (int*)ws;                      ws += (size_t)NB2 * 4;

    // --- CSR build: hist -> bucket scan -> bucket scatter -> per-bucket sort
    hipMemsetAsync(ghist, 0, (size_t)NB2 * 4, stream);
    k_hist<<<512, 256, 0, stream>>>(adj_row, ghist, nnz);
    k_top<<<1, 512, 0, stream>>>(ghist, bstart, bcursor, nnz);
    int sc_blocks = (nnz + SC_CHUNK - 1) / SC_CHUNK;
    k_scat1<<<sc_blocks, 256, 0, stream>>>(adj_row, adj_col, adj_vals,
                                           bcursor, packed, nnz);
    k_sort<<<NB2, 1024, 0, stream>>>(packed, bstart, bkv, rowptr, nnz);

    // --- 3 propagation layers (pull); layer 1 reads ego directly, seeds acc
    const int grid = (N_NODES + 3) / 4;
    lgcn_spmm_pull<true,  false><<<grid, 256, 0, stream>>>(bkv, rowptr, user_emb, item_emb, h1, acc);
    lgcn_spmm_pull<false, false><<<grid, 256, 0, stream>>>(bkv, rowptr, h1, nullptr, h2, acc);
    lgcn_spmm_pull<false, true ><<<grid, 256, 0, stream>>>(bkv, rowptr, h2, nullptr, nullptr, acc);
}